// Round 8
// baseline (1989.945 us; speedup 1.0000x reference)
//
#include <hip/hip_runtime.h>
#include <hip/hip_bf16.h>
#include <math.h>

typedef __hip_bfloat16 bf16;

__device__ __forceinline__ float b2f(bf16 x){ return __bfloat162float(x); }
__device__ __forceinline__ bf16  f2b(float x){ return __float2bfloat16(x); }

// raw-bits bf16 helpers (RNE, finite inputs)
__device__ __forceinline__ short f2bs(float f){
    unsigned u = __float_as_uint(f);
    u += 0x7fffu + ((u >> 16) & 1u);
    return (short)(u >> 16);
}
__device__ __forceinline__ float bs2f(short s){
    return __uint_as_float(((unsigned)(unsigned short)s) << 16);
}

#define NUSERS   10000
#define NPOIS    50000
#define SEQL     100
#define NNODES   60001
#define BATCH    1024
#define NNZG     1920000
#define NNZH     1600000
#define BL       (BATCH*SEQL)          // 102400
#define BLD      (BL*128)              // 13,107,200 elems
#define NND      (NNODES*128)          // 7,680,128
#define CN       (60000*128)           // 7,680,000
#define PD       (NPOIS*128)           // 6,400,000

__device__ __forceinline__ void  stc(bf16* p,  float v){ *p = f2b(v); }
__device__ __forceinline__ void  stc(float* p, float v){ *p = v; }

typedef __attribute__((ext_vector_type(8))) short s16x8;
typedef __attribute__((ext_vector_type(4))) float f32x4;

// ---------- zero-fill (16B granules) ----------
__global__ __launch_bounds__(256) void k_zero(float* __restrict__ p, int n4){
    int i = blockIdx.x*256 + threadIdx.x;
    if (i < n4) ((float4*)p)[i] = make_float4(0.f,0.f,0.f,0.f);
}

// ---------- 16B copy ----------
__global__ __launch_bounds__(256) void k_copy16(ulong2* __restrict__ dst,
                                                const ulong2* __restrict__ src, int n16){
    int i = blockIdx.x*256 + threadIdx.x;
    if (i < n16) dst[i] = src[i];
}

// ---------- init: nodes(bf16)=src, acc(f32)=src ----------
__global__ __launch_bounds__(256) void k_init(bf16* __restrict__ nodes, float* __restrict__ acc,
                                              const float* __restrict__ src, int n){
    int i = blockIdx.x*256 + threadIdx.x;
    if (i >= n) return;
    float v = src[i];
    nodes[i] = f2b(v); acc[i] = v;
}

// ---------- row gather f32 table -> f32 dst ----------
__global__ __launch_bounds__(256) void k_gather_f(float* __restrict__ dst,
                                                  const float* __restrict__ table,
                                                  const int* __restrict__ idx, int rows){
    int gid = blockIdx.x*256 + threadIdx.x;
    if (gid >= rows*128) return;
    int r = gid >> 7, c = gid & 127;
    dst[(size_t)r*128 + c] = table[(size_t)idx[r]*128 + c];
}

// ================= fused gather + geo + fc_geo + tot =================
__global__ __launch_bounds__(256) void k_mgeo2(bf16* __restrict__ tot,
                                               const bf16* __restrict__ nodes,
                                               const int* __restrict__ seqs,
                                               const float* __restrict__ adj,
                                               const float* __restrict__ fcw,
                                               const float* __restrict__ fcb,
                                               const float* __restrict__ posl){
    __shared__ short st[128*104];     // seq^T (col-major), pitch 104
    __shared__ short gt[112*136];     // geo tile bf16, pitch 136
    int b = blockIdx.x, tid = threadIdx.x;
    const int* sq = seqs + b*SEQL;
    for (int i = tid; i < SEQL*128; i += 256){
        int j = i >> 7, c = i & 127;
        st[c*104 + j] = ((const short*)nodes)[(size_t)sq[j]*128 + c];
    }
    for (int i = tid; i < 128*4; i += 256){ int c = i>>2, r = i&3; st[c*104 + 100 + r] = 0; }
    __syncthreads();
    int wv = tid>>6, lane = tid&63, lr = lane&15, lk = lane>>4;
    const s16x8 zf = {0,0,0,0,0,0,0,0};
    s16x8 bfr[2][4];
    #pragma unroll
    for (int t = 0; t < 2; t++){
        int nt = wv*2 + t;
        #pragma unroll
        for (int kc = 0; kc < 4; kc++)
            bfr[t][kc] = *(const s16x8*)&st[(nt*16+lr)*104 + kc*32 + lk*8];
    }
    const float* ab = adj + (size_t)b*SEQL*SEQL;
    for (int mt = 0; mt < 7; mt++){
        int ar = min(mt*16 + lr, SEQL-1);          // clamp pad rows (discarded later)
        s16x8 ah[4], al[4];
        #pragma unroll
        for (int kc = 0; kc < 4; kc++){
            float av[8] = {0,0,0,0,0,0,0,0};
            if (kc < 3){
                const float* ap = ab + (size_t)ar*SEQL + kc*32 + lk*8;
                float4 a0 = *(const float4*)ap;
                float4 a1 = *(const float4*)(ap + 4);
                av[0]=a0.x; av[1]=a0.y; av[2]=a0.z; av[3]=a0.w;
                av[4]=a1.x; av[5]=a1.y; av[6]=a1.z; av[7]=a1.w;
            } else if (lk == 0){
                float4 a0 = *(const float4*)(ab + (size_t)ar*SEQL + 96);
                av[0]=a0.x; av[1]=a0.y; av[2]=a0.z; av[3]=a0.w;   // k=96..99
            }
            s16x8 h = zf, l = zf;
            #pragma unroll
            for (int j = 0; j < 8; j++){
                short hb = f2bs(av[j]);
                h[j] = hb;
                l[j] = f2bs(av[j] - bs2f(hb));
            }
            ah[kc] = h; al[kc] = l;
        }
        f32x4 c0 = {0.f,0.f,0.f,0.f}, c1 = {0.f,0.f,0.f,0.f};
        #pragma unroll
        for (int kc = 0; kc < 4; kc++){
            c0 = __builtin_amdgcn_mfma_f32_16x16x32_bf16(ah[kc], bfr[0][kc], c0, 0,0,0);
            c0 = __builtin_amdgcn_mfma_f32_16x16x32_bf16(al[kc], bfr[0][kc], c0, 0,0,0);
            c1 = __builtin_amdgcn_mfma_f32_16x16x32_bf16(ah[kc], bfr[1][kc], c1, 0,0,0);
            c1 = __builtin_amdgcn_mfma_f32_16x16x32_bf16(al[kc], bfr[1][kc], c1, 0,0,0);
        }
        #pragma unroll
        for (int t = 0; t < 2; t++){
            f32x4 cc = t ? c1 : c0;
            int col = wv*32 + t*16 + lr;
            #pragma unroll
            for (int r = 0; r < 4; r++){
                int row = mt*16 + lk*4 + r;          // store ALL rows incl. pad (finite)
                gt[row*136 + col] = f2bs(cc[r]);
            }
        }
    }
    // phase-2 W fragments (fc_geo_w, wstride=128)
    s16x8 wh[2][4], wl[2][4];
    int n0 = wv*32;
    #pragma unroll
    for (int t = 0; t < 2; t++){
        #pragma unroll
        for (int ks = 0; ks < 4; ks++){
            const float* wp = fcw + (size_t)(n0 + t*16 + lr)*128 + ks*32 + lk*8;
            float4 w0 = *(const float4*)(wp);
            float4 w1 = *(const float4*)(wp + 4);
            float wf[8] = {w0.x,w0.y,w0.z,w0.w,w1.x,w1.y,w1.z,w1.w};
            s16x8 h, l;
            #pragma unroll
            for (int j = 0; j < 8; j++){
                short hb = f2bs(wf[j]);
                h[j] = hb;
                l[j] = f2bs(wf[j] - bs2f(hb));
            }
            wh[t][ks] = h; wl[t][ks] = l;
        }
    }
    __syncthreads();
    for (int mt = 0; mt < 7; mt++){
        s16x8 ah[4];
        #pragma unroll
        for (int ks = 0; ks < 4; ks++)
            ah[ks] = *(const s16x8*)&gt[(mt*16+lr)*136 + ks*32 + lk*8];
        f32x4 c0 = {0.f,0.f,0.f,0.f}, c1 = {0.f,0.f,0.f,0.f};
        #pragma unroll
        for (int ks = 0; ks < 4; ks++){
            c0 = __builtin_amdgcn_mfma_f32_16x16x32_bf16(ah[ks], wh[0][ks], c0, 0,0,0);
            c0 = __builtin_amdgcn_mfma_f32_16x16x32_bf16(ah[ks], wl[0][ks], c0, 0,0,0);
            c1 = __builtin_amdgcn_mfma_f32_16x16x32_bf16(ah[ks], wh[1][ks], c1, 0,0,0);
            c1 = __builtin_amdgcn_mfma_f32_16x16x32_bf16(ah[ks], wl[1][ks], c1, 0,0,0);
        }
        #pragma unroll
        for (int t = 0; t < 2; t++){
            f32x4 cc = t ? c1 : c0;
            int col = n0 + t*16 + lr;
            float bv = fcb[col];
            #pragma unroll
            for (int r = 0; r < 4; r++){
                int row = mt*16 + lk*4 + r;
                if (row < SEQL){
                    float v = fmaxf(cc[r] + bv, 0.f);
                    v += bs2f(st[col*104 + row]) + posl[(row+1)*128 + col];
                    tot[(size_t)b*SEQL*128 + (size_t)row*128 + col] = f2b(v);
                }
            }
        }
    }
}

// ================= MFMA GEMM =================
// C[row,128] = epilogue( A[M,128] @ W[n, wstride; +woff]^T ), row = outidx?outidx[m]:m
template<typename TA, typename TC>
__global__ __launch_bounds__(256) void k_mgemm(const TA* __restrict__ A,
                                               const float* __restrict__ W, int wstride, int woff,
                                               const float* __restrict__ bias, int boff,
                                               TC* __restrict__ C, int act,
                                               const float* __restrict__ add1, int addmode,
                                               const int* __restrict__ masks,
                                               const int* __restrict__ outidx){
    constexpr bool A_BF = (sizeof(TA) == 2);
    int tid  = threadIdx.x;
    int wv   = tid >> 6;
    int lane = tid & 63;
    int lr   = lane & 15;
    int lk   = lane >> 4;
    int n0   = wv * 32;

    s16x8 wh[2][4], wl[2][4];
    #pragma unroll
    for (int t = 0; t < 2; t++){
        #pragma unroll
        for (int ks = 0; ks < 4; ks++){
            const float* wp = W + (size_t)(n0 + t*16 + lr)*wstride + woff + ks*32 + lk*8;
            float4 w0 = *(const float4*)(wp);
            float4 w1 = *(const float4*)(wp + 4);
            float wf[8] = {w0.x,w0.y,w0.z,w0.w,w1.x,w1.y,w1.z,w1.w};
            s16x8 h, l;
            #pragma unroll
            for (int j = 0; j < 8; j++){
                short hb = f2bs(wf[j]);
                h[j] = hb;
                l[j] = f2bs(wf[j] - bs2f(hb));
            }
            wh[t][ks] = h; wl[t][ks] = l;
        }
    }

    size_t mblk = (size_t)blockIdx.x * 128;
    for (int it = 0; it < 8; it++){
        size_t m0 = mblk + (size_t)it*16;
        s16x8 ah[4], al[4];
        #pragma unroll
        for (int ks = 0; ks < 4; ks++){
            if constexpr (A_BF){
                ah[ks] = *(const s16x8*)((const short*)A + (m0 + lr)*128 + ks*32 + lk*8);
            } else {
                const float* ap = (const float*)A + (m0 + lr)*128 + ks*32 + lk*8;
                float4 a0 = *(const float4*)(ap);
                float4 a1 = *(const float4*)(ap + 4);
                float av[8] = {a0.x,a0.y,a0.z,a0.w,a1.x,a1.y,a1.z,a1.w};
                s16x8 h, l;
                #pragma unroll
                for (int j = 0; j < 8; j++){
                    short hb = f2bs(av[j]);
                    h[j] = hb;
                    l[j] = f2bs(av[j] - bs2f(hb));
                }
                ah[ks] = h; al[ks] = l;
            }
        }
        __syncthreads();   // in-place safety: all reads of stripe before any writes
        f32x4 c0 = {0.f,0.f,0.f,0.f}, c1 = {0.f,0.f,0.f,0.f};
        #pragma unroll
        for (int ks = 0; ks < 4; ks++){
            c0 = __builtin_amdgcn_mfma_f32_16x16x32_bf16(ah[ks], wh[0][ks], c0, 0, 0, 0);
            c0 = __builtin_amdgcn_mfma_f32_16x16x32_bf16(ah[ks], wl[0][ks], c0, 0, 0, 0);
            c1 = __builtin_amdgcn_mfma_f32_16x16x32_bf16(ah[ks], wh[1][ks], c1, 0, 0, 0);
            c1 = __builtin_amdgcn_mfma_f32_16x16x32_bf16(ah[ks], wl[1][ks], c1, 0, 0, 0);
            if constexpr (!A_BF){
                c0 = __builtin_amdgcn_mfma_f32_16x16x32_bf16(al[ks], wh[0][ks], c0, 0, 0, 0);
                c1 = __builtin_amdgcn_mfma_f32_16x16x32_bf16(al[ks], wh[1][ks], c1, 0, 0, 0);
            }
        }
        #pragma unroll
        for (int t = 0; t < 2; t++){
            f32x4 cc = t ? c1 : c0;
            int c = n0 + t*16 + lr;
            float bv = bias ? bias[boff + c] : 0.f;
            #pragma unroll
            for (int r4 = 0; r4 < 4; r4++){
                int m = (int)m0 + lk*4 + r4;
                float v = cc[r4] + bv;
                if (addmode == 1){
                    int l = m % SEQL;
                    int p = (l+1) * masks[m];
                    v += add1[p*128 + c];
                } else if (addmode == 2){
                    v += add1[(m/SEQL)*128 + c];
                }
                if (act == 1) v = fmaxf(v, 0.f);
                else if (act == 2) v = tanhf(v);
                else if (act == 3) v = 1.f/(1.f+__expf(-v));
                size_t orow = outidx ? (size_t)outidx[m] : (size_t)m;
                stc(&C[orow*128 + c], v);
            }
        }
    }
}

// ================= fused nh2 GEMM + beta =================
// beta[m] = sum_c sigmoid( nh[m]@glu1_w[c] + glu1_b[c] + hproj[m/SEQL,c] ) * w2[c]
// nh2 is never materialized.
__global__ __launch_bounds__(256) void k_nh2beta(const bf16* __restrict__ A,
                                                 const float* __restrict__ W,
                                                 const float* __restrict__ bias,
                                                 const float* __restrict__ hproj,
                                                 const float* __restrict__ w2,
                                                 float* __restrict__ beta){
    __shared__ float red[16];
    int tid  = threadIdx.x;
    int wv   = tid >> 6;
    int lane = tid & 63;
    int lr   = lane & 15;
    int lk   = lane >> 4;
    int n0   = wv * 32;

    s16x8 wh[2][4], wl[2][4];
    #pragma unroll
    for (int t = 0; t < 2; t++){
        #pragma unroll
        for (int ks = 0; ks < 4; ks++){
            const float* wp = W + (size_t)(n0 + t*16 + lr)*128 + ks*32 + lk*8;
            float4 w0 = *(const float4*)(wp);
            float4 w1 = *(const float4*)(wp + 4);
            float wf[8] = {w0.x,w0.y,w0.z,w0.w,w1.x,w1.y,w1.z,w1.w};
            s16x8 h, l;
            #pragma unroll
            for (int j = 0; j < 8; j++){
                short hb = f2bs(wf[j]);
                h[j] = hb;
                l[j] = f2bs(wf[j] - bs2f(hb));
            }
            wh[t][ks] = h; wl[t][ks] = l;
        }
    }

    size_t mblk = (size_t)blockIdx.x * 128;
    for (int it = 0; it < 8; it++){
        size_t m0 = mblk + (size_t)it*16;
        s16x8 ah[4];
        #pragma unroll
        for (int ks = 0; ks < 4; ks++)
            ah[ks] = *(const s16x8*)((const short*)A + (m0 + lr)*128 + ks*32 + lk*8);
        if (tid < 16) red[tid] = 0.f;
        __syncthreads();
        f32x4 c0 = {0.f,0.f,0.f,0.f}, c1 = {0.f,0.f,0.f,0.f};
        #pragma unroll
        for (int ks = 0; ks < 4; ks++){
            c0 = __builtin_amdgcn_mfma_f32_16x16x32_bf16(ah[ks], wh[0][ks], c0, 0, 0, 0);
            c0 = __builtin_amdgcn_mfma_f32_16x16x32_bf16(ah[ks], wl[0][ks], c0, 0, 0, 0);
            c1 = __builtin_amdgcn_mfma_f32_16x16x32_bf16(ah[ks], wh[1][ks], c1, 0, 0, 0);
            c1 = __builtin_amdgcn_mfma_f32_16x16x32_bf16(ah[ks], wl[1][ks], c1, 0, 0, 0);
        }
        float pr[4] = {0.f,0.f,0.f,0.f};
        #pragma unroll
        for (int t = 0; t < 2; t++){
            f32x4 cc = t ? c1 : c0;
            int c = n0 + t*16 + lr;
            float bv = bias[c];
            float wc = w2[c];
            #pragma unroll
            for (int r4 = 0; r4 < 4; r4++){
                int m = (int)m0 + lk*4 + r4;
                float v = cc[r4] + bv + hproj[(m/SEQL)*128 + c];
                v = 1.f/(1.f+__expf(-v));
                pr[r4] += v * wc;
            }
        }
        #pragma unroll
        for (int s = 1; s < 16; s <<= 1){
            #pragma unroll
            for (int r4 = 0; r4 < 4; r4++) pr[r4] += __shfl_xor(pr[r4], s);
        }
        if (lr == 0){
            #pragma unroll
            for (int r4 = 0; r4 < 4; r4++) atomicAdd(&red[lk*4 + r4], pr[r4]);
        }
        __syncthreads();
        if (tid < 16) beta[m0 + tid] = red[tid];
    }
}

// ================= MFMA attention + fused column-mean =================
__global__ __launch_bounds__(256) void k_mattn(float* __restrict__ Omean,
                                               const bf16* __restrict__ Qq,
                                               const bf16* __restrict__ Qk,
                                               const bf16* __restrict__ Qv){
    __shared__ short Vt[128*104];      // V^T, pitch 104
    __shared__ short Ph[4][16*136];    // per-wave P stripe (hi), pitch 136
    __shared__ short Pl[4][16*136];    // per-wave P stripe (lo)
    int b = blockIdx.x, tid = threadIdx.x;
    const short* vsrc = (const short*)(Qv + (size_t)b*SEQL*128);
    for (int i = tid; i < SEQL*128; i += 256){ int j = i>>7, c = i&127; Vt[c*104 + j] = vsrc[i]; }
    for (int i = tid; i < 128*4; i += 256){ int c = i>>2, r = i&3; Vt[c*104 + 100 + r] = 0; }
    int wv = tid>>6, lane = tid&63, lr = lane&15, lk = lane>>4;
    short* phw = Ph[wv];
    short* plw = Pl[wv];
    for (int i = lane; i < 16*136; i += 64){ phw[i] = 0; plw[i] = 0; }
    __syncthreads();

    const s16x8 zf = {0,0,0,0,0,0,0,0};
    size_t rowbase = (size_t)b*SEQL*128;
    bool kreal = (lk < 2);
    for (int hh = 0; hh < 2; hh++){
        int h = wv*2 + hh;
        int hd = h*16 + lk*8;
        s16x8 kf[7];
        #pragma unroll
        for (int nt = 0; nt < 7; nt++){
            int kr = min(nt*16 + lr, SEQL-1);
            kf[nt] = kreal ? *(const s16x8*)((const short*)Qk + rowbase + (size_t)kr*128 + hd) : zf;
        }
        s16x8 vf[4];
        #pragma unroll
        for (int kc = 0; kc < 4; kc++)
            vf[kc] = *(const s16x8*)&Vt[(h*16+lr)*104 + kc*32 + lk*8];

        float msum = 0.f;     // partial column-mean accumulator (col = h*16+lr)
        for (int mt = 0; mt < 7; mt++){
            int qr = min(mt*16 + lr, SEQL-1);
            s16x8 qf = kreal ? *(const s16x8*)((const short*)Qq + rowbase + (size_t)qr*128 + hd) : zf;
            f32x4 sc[7];
            #pragma unroll
            for (int nt = 0; nt < 7; nt++){
                f32x4 z = {0.f,0.f,0.f,0.f};
                sc[nt] = __builtin_amdgcn_mfma_f32_16x16x32_bf16(qf, kf[nt], z, 0,0,0);
            }
            float mx[4] = {-1e30f,-1e30f,-1e30f,-1e30f};
            #pragma unroll
            for (int nt = 0; nt < 7; nt++){
                bool masked = (nt == 6) && (lr >= 4);   // cols >= 100
                #pragma unroll
                for (int r = 0; r < 4; r++){
                    float s = masked ? -1e30f : sc[nt][r]*0.25f;
                    sc[nt][r] = s;
                    mx[r] = fmaxf(mx[r], s);
                }
            }
            #pragma unroll
            for (int m = 1; m < 16; m <<= 1){
                #pragma unroll
                for (int r = 0; r < 4; r++) mx[r] = fmaxf(mx[r], __shfl_xor(mx[r], m));
            }
            float sm[4] = {0.f,0.f,0.f,0.f};
            #pragma unroll
            for (int nt = 0; nt < 7; nt++){
                #pragma unroll
                for (int r = 0; r < 4; r++){
                    float p = __expf(sc[nt][r] - mx[r]);
                    sc[nt][r] = p; sm[r] += p;
                }
            }
            #pragma unroll
            for (int m = 1; m < 16; m <<= 1){
                #pragma unroll
                for (int r = 0; r < 4; r++) sm[r] += __shfl_xor(sm[r], m);
            }
            float inv[4];
            #pragma unroll
            for (int r = 0; r < 4; r++) inv[r] = 1.f/sm[r];
            #pragma unroll
            for (int nt = 0; nt < 7; nt++){
                #pragma unroll
                for (int r = 0; r < 4; r++){
                    float p = sc[nt][r]*inv[r];
                    short hb = f2bs(p);
                    int pa = (lk*4+r)*136 + nt*16 + lr;
                    phw[pa] = hb;
                    plw[pa] = f2bs(p - bs2f(hb));
                }
            }
            f32x4 oa = {0.f,0.f,0.f,0.f};
            #pragma unroll
            for (int kc = 0; kc < 4; kc++){
                s16x8 pah = *(const s16x8*)&phw[lr*136 + kc*32 + lk*8];
                s16x8 pal = *(const s16x8*)&plw[lr*136 + kc*32 + lk*8];
                oa = __builtin_amdgcn_mfma_f32_16x16x32_bf16(pah, vf[kc], oa, 0,0,0);
                oa = __builtin_amdgcn_mfma_f32_16x16x32_bf16(pal, vf[kc], oa, 0,0,0);
            }
            #pragma unroll
            for (int r = 0; r < 4; r++){
                int row = mt*16 + lk*4 + r;
                if (row < SEQL) msum += oa[r];
            }
        }
        msum += __shfl_xor(msum, 16);
        msum += __shfl_xor(msum, 32);
        if (lk == 0) Omean[(size_t)b*128 + h*16 + lr] = msum * (1.f/(float)SEQL);
    }
}

// ================= CSR build (binned, write-amplification-free) =================

__global__ __launch_bounds__(256) void k_hist(int* __restrict__ cnt,
                                              const int* __restrict__ rows, int nnz){
    int e = blockIdx.x*256 + threadIdx.x;
    if (e < nnz) atomicAdd(&cnt[rows[e]], 1);
}

__global__ __launch_bounds__(1024) void k_scan(int* __restrict__ cnt,
                                               int* __restrict__ rowptr, int nrows){
    __shared__ int part[1024];
    int tid = threadIdx.x;
    int chunk = (nrows + 1023) >> 10;
    int s = tid*chunk, e = min(s+chunk, nrows);
    int sum = 0;
    for (int i = s; i < e; i++) sum += cnt[i];
    part[tid] = sum;
    __syncthreads();
    for (int off = 1; off < 1024; off <<= 1){
        int add = (tid >= off) ? part[tid-off] : 0;
        __syncthreads();
        part[tid] += add;
        __syncthreads();
    }
    int run = part[tid] - sum;
    for (int i = s; i < e; i++){
        int c = cnt[i];
        rowptr[i] = run;
        cnt[i]    = run;
        run += c;
    }
    if (tid == 0) rowptr[nrows] = part[1023];
}

// curB[b] = rowptr[b*16]  (bucket = 16 consecutive rows)
__global__ __launch_bounds__(256) void k_initcurB(int* __restrict__ curB,
                                                  const int* __restrict__ rowptr, int nb){
    int b = blockIdx.x*256 + threadIdx.x;
    if (b < nb) curB[b] = rowptr[b << 4];
}

// phase A: append edges to their bucket region (sequential per-bucket writes).
// packs rowlo (4b) into bits 17-20 of the col word (col < 2^17).
__global__ __launch_bounds__(256) void k_append(int2* __restrict__ stage,
                                                int* __restrict__ curB,
                                                const int* __restrict__ rows,
                                                const int* __restrict__ cols,
                                                const float* __restrict__ vals, int nnz){
    int e = blockIdx.x*256 + threadIdx.x;
    if (e >= nnz) return;
    int r = rows[e];
    int p = atomicAdd(&curB[r >> 4], 1);
    stage[p] = make_int2(cols[e] | ((r & 15) << 17), __float_as_int(vals[e]));
}

// phase B: one block per bucket; LDS row cursors; writes confined to the
// bucket's ~4KB CSR window (L2-resident, full-line writebacks).
__global__ __launch_bounds__(256) void k_place(int2* __restrict__ cv,
                                               const int* __restrict__ rowptr,
                                               const int2* __restrict__ stage, int nrows){
    __shared__ int cur[16];
    int b = blockIdx.x, tid = threadIdx.x;
    int r0 = b << 4;
    if (tid < 16) cur[tid] = rowptr[r0 + tid];
    __syncthreads();
    int s = rowptr[r0], e = rowptr[min(r0 + 16, nrows)];
    for (int i = s + tid; i < e; i += 256){
        int2 w = stage[i];
        int p = atomicAdd(&cur[(w.x >> 17) & 15], 1);
        cv[p] = make_int2(w.x & 0x1FFFF, w.y);
    }
}

// one wave per row, 8 edge-slots x 8 lanes; lane loads 32B (16 bf16) of x-row.
__global__ __launch_bounds__(256) void k_spmm_csr(bf16* __restrict__ yb,
                                                  float* __restrict__ acc,
                                                  const int* __restrict__ rowptr,
                                                  const int2* __restrict__ cv,
                                                  const bf16* __restrict__ x, int nrows){
    int row = blockIdx.x*4 + (threadIdx.x >> 6);
    if (row >= nrows) return;
    int lane = threadIdx.x & 63;
    int g = lane >> 3;           // edge-slot 0..7
    int t = lane & 7;            // col-group: cols t*16 .. t*16+15
    int s = rowptr[row], e = rowptr[row+1];
    float a[16];
    #pragma unroll
    for (int j = 0; j < 16; j++) a[j] = 0.f;
    for (int i = s + g; i < e; i += 8){
        int2 p = cv[i];
        float v = __int_as_float(p.y);
        const unsigned* xp = (const unsigned*)(x + (size_t)p.x*128 + t*16);
        uint4 u0 = *(const uint4*)xp;
        uint4 u1 = *(const uint4*)(xp + 4);
        unsigned w[8] = {u0.x,u0.y,u0.z,u0.w,u1.x,u1.y,u1.z,u1.w};
        #pragma unroll
        for (int j = 0; j < 8; j++){
            a[2*j]   += v * __uint_as_float((w[j] & 0xffffu) << 16);
            a[2*j+1] += v * __uint_as_float(w[j] & 0xffff0000u);
        }
    }
    #pragma unroll
    for (int j = 0; j < 16; j++){
        a[j] += __shfl_xor(a[j], 8);
        a[j] += __shfl_xor(a[j], 16);
        a[j] += __shfl_xor(a[j], 32);
    }
    if (g == 0){
        s16x8 o0, o1;
        #pragma unroll
        for (int j = 0; j < 8; j++){ o0[j] = f2bs(a[j]); o1[j] = f2bs(a[8+j]); }
        short* yp = (short*)yb + (size_t)row*128 + t*16;
        *(s16x8*)yp = o0;
        *(s16x8*)(yp + 8) = o1;
        float* ap = acc + (size_t)row*128 + t*16;
        #pragma unroll
        for (int q = 0; q < 4; q++){
            float4 c = ((float4*)ap)[q];
            c.x += a[q*4+0]; c.y += a[q*4+1]; c.z += a[q*4+2]; c.w += a[q*4+3];
            ((float4*)ap)[q] = c;
        }
    }
}

__global__ __launch_bounds__(256) void k_scale(float* __restrict__ a, int n){
    int i = blockIdx.x*256 + threadIdx.x;
    if (i < n) a[i] *= (1.f/3.f);
}

// ---------- global branch init ----------
__global__ __launch_bounds__(256) void k_initg(bf16* __restrict__ xg, float* __restrict__ accg,
                                               const float* __restrict__ ne, int n){
    int i = blockIdx.x*256 + threadIdx.x;
    if (i >= n) return;
    float v = ne[(size_t)NUSERS*128 + i];
    xg[i] = f2b(v); accg[i] = v;
}

// ---------- fusion: acc_poi += accg/3; emit pois output (f32!) ----------
__global__ __launch_bounds__(256) void k_fusion(float* __restrict__ accP,
                                                const float* __restrict__ accg,
                                                float* __restrict__ outp, int n){
    int i = blockIdx.x*256 + threadIdx.x;
    if (i >= n) return;
    float v = accP[i] + accg[i]*(1.f/3.f);
    accP[i] = v;
    outp[i] = v;
}

// ================= HEAD =================

__global__ __launch_bounds__(128) void k_hs(float* __restrict__ hs, const float* __restrict__ sh,
                                            const float* __restrict__ lens){
    int b = blockIdx.x, c = threadIdx.x;
    const float* p = sh + (size_t)b*SEQL*128 + c;
    float sum = 0.f;
    for (int l = 0; l < SEQL; l++) sum += p[l*128];
    hs[b*128 + c] = sum / lens[b];
}

__global__ __launch_bounds__(128) void k_posw(float* __restrict__ posW,
                                              const float* __restrict__ pg,
                                              const float* __restrict__ w1w){
    __shared__ float sm[128];
    int p = blockIdx.x, n = threadIdx.x;
    sm[n] = pg[p*128 + n];
    __syncthreads();
    const float* wr = w1w + (size_t)n*256;
    float s = 0.f;
    for (int k = 0; k < 128; k++) s += sm[k]*wr[k];
    posW[p*128 + n] = s;
}

__global__ __launch_bounds__(128) void k_final(float* __restrict__ out,
                                               const float* __restrict__ beta,
                                               const float* __restrict__ seqh,
                                               const float* __restrict__ acc,
                                               const int* __restrict__ uidx){
    int b = blockIdx.x, c = threadIdx.x;
    const float* sh = seqh + (size_t)b*SEQL*128 + c;
    const float* bp = beta + b*SEQL;
    float sel = 0.f;
    for (int l = 0; l < SEQL; l++) sel += bp[l]*sh[l*128];
    out[b*128 + c] = sel + acc[(size_t)uidx[b]*128 + c];
}

extern "C" void kernel_launch(void* const* d_in, const int* in_sizes, int n_in,
                              void* d_out, int out_size, void* d_ws, size_t ws_size,
                              hipStream_t stream){
    const float* nodes_emb     = (const float*)d_in[0];
    const float* pos_emb_local = (const float*)d_in[1];
    const float* fc_geo_w      = (const float*)d_in[2];
    const float* fc_geo_b      = (const float*)d_in[3];
    const float* in_proj_w     = (const float*)d_in[4];
    const float* in_proj_b     = (const float*)d_in[5];
    const float* out_proj_w    = (const float*)d_in[6];
    const float* out_proj_b    = (const float*)d_in[7];
    const float* pos_emb_glob  = (const float*)d_in[8];
    const float* w1_w          = (const float*)d_in[9];
    const float* w1_b          = (const float*)d_in[10];
    const float* w_2           = (const float*)d_in[11];
    const float* glu1_w        = (const float*)d_in[12];
    const float* glu1_b        = (const float*)d_in[13];
    const float* glu2_w        = (const float*)d_in[14];
    const int*   G_rows        = (const int*)d_in[15];
    const int*   G_cols        = (const int*)d_in[16];
    const float* G_vals        = (const float*)d_in[17];
    const int*   HG_rows       = (const int*)d_in[18];
    const int*   HG_cols       = (const int*)d_in[19];
    const float* HG_vals       = (const float*)d_in[20];
    const int*   seqs          = (const int*)d_in[21];
    const int*   masks         = (const int*)d_in[22];
    const float* adjs          = (const float*)d_in[23];
    const int*   uidx          = (const int*)d_in[24];
    const float* lens          = (const float*)d_in[25];
    const int*   rev_seqs      = (const int*)d_in[26];
    float* out = (float*)d_out;   // OUTPUT IS FLOAT32

    // ---- workspace layout ----
    char* base = (char*)d_ws;
    bf16*  nodes = (bf16*)base;                               // [0, 15,360,256)
    float* acc   = (float*)(base + 15360256);                 // [.., 46,080,768)
    char*  R     = base + 15360256 + 30720512;                // [46,080,768, 124,723,968)
    // layer-phase aliases inside R:
    bf16* P1 = (bf16*)R;          // BLD bf16
    bf16* P2 = P1 + BLD;
    bf16* P3 = P2 + BLD;
    // G-build (pre-layers): stage in R (free)
    int2*  stageG = (int2*)R;                        // 15,360,000 (pre-layer only)
    // spmm-window alias (P1 dead):
    bf16*  xsnap = (bf16*)R;                         // 60000-row bf16 snapshot
    // global-phase aliases:
    bf16*  xg     = (bf16*)R;                        // PD bf16
    bf16*  xsnapg = (bf16*)(R + 12800000);           // PD bf16 snapshot
    float* accg = (float*)(R + 12800000 + 25600000); // PD f32 -> ends 64,000,000
    int2*  Hcv   = (int2*)(R + 64000000);            // 12,800,000 -> 76,800,000
    int*   Hptr  = (int*)(R + 76800000);             // 200,004
    int*   cntH  = (int*)(R + 77000016);             // 200,000
    int*   curBH = (int*)(R + 77200016);             // 12,500 -> 77,212,516
    int2*  stageH = (int2*)out;                      // 12,800,000 (Gcv dead by then)
    // head-phase aliases:
    float* H1f  = (float*)R;                         // BLD f32
    bf16*  nh   = (bf16*)(R + 52428800);             // BLD bf16 -> ends 78,643,200
    float* hs    = (float*)base;                     // small bufs in dead nodes region
    float* hproj = (float*)(base + 524288);
    float* posW  = (float*)(base + 1048576);
    float* betaB = (float*)(base + 1100288);
    // G-CSR + Omean scratch in OUT buffer (dead until k_fusion/k_final):
    char*  ob    = (char*)out;
    int2*  Gcv   = (int2*)ob;                        // 15,360,000
    int*   Gptr  = (int*)(ob + 15360000);            // 240,004
    int*   cntG  = (int*)(ob + 15600016);            // 240,000
    int*   curBG = (int*)(ob + 15840016);            // 15,000 -> 15,855,016
    float* Omean = (float*)(ob + 15856000);          // 524,288 -> 16,380,288

    auto gemm = [&](const bf16* A, const float* W, int wstride, int woff,
                    const float* bias, int boff, bf16* Cp, int act){
        k_mgemm<bf16,bf16><<<dim3(BL/128), dim3(256), 0, stream>>>(
            A, W, wstride, woff, bias, boff, Cp, act, nullptr, 0, nullptr, nullptr);
    };

    // init: nodes (bf16) = nodes_emb, acc (f32) = nodes_emb
    k_init<<<dim3((NND+255)/256), dim3(256), 0, stream>>>(nodes, acc, nodes_emb, NND);

    // ---- build G CSR ONCE (binned two-phase placement) ----
    k_zero<<<dim3((15000+255)/256), dim3(256), 0, stream>>>((float*)cntG, 15000); // 60000 ints
    k_hist<<<dim3(NNZG/256), dim3(256), 0, stream>>>(cntG, G_rows, NNZG);
    k_scan<<<dim3(1), dim3(1024), 0, stream>>>(cntG, Gptr, 60000);
    k_initcurB<<<dim3(15), dim3(256), 0, stream>>>(curBG, Gptr, 3750);
    k_append<<<dim3(NNZG/256), dim3(256), 0, stream>>>(stageG, curBG, G_rows, G_cols, G_vals, NNZG);
    k_place<<<dim3(3750), dim3(256), 0, stream>>>(Gcv, Gptr, stageG, 60000);

    for (int layer = 0; layer < 2; layer++){
        // fused gather + geo + fc_geo + tot -> P3
        k_mgeo2<<<dim3(BATCH), dim3(256), 0, stream>>>(P3, nodes, seqs, adjs,
                                                       fc_geo_w, fc_geo_b, pos_emb_local);
        gemm(P3, in_proj_w, 128, 0,       in_proj_b, 0,   P1, 0); // Q
        gemm(P3, in_proj_w, 128, 128*128, in_proj_b, 128, P2, 0); // K
        gemm(P3, in_proj_w, 128, 256*128, in_proj_b, 256, P3, 0); // V in-place
        // attention with fused column-mean (O never materialized)
        k_mattn<<<dim3(BATCH), dim3(256), 0, stream>>>(Omean, P1, P2, P3);
        // users = Omean @ outW^T + outB, scattered into nodes[uidx]
        k_mgemm<float,bf16><<<dim3(BATCH/128), dim3(256), 0, stream>>>(
            Omean, out_proj_w, 128, 0, out_proj_b, 0, nodes, 0, nullptr, 0, nullptr, uidx);
        // snapshot x, then SpMM writes nodes (bf16) + acc += directly
        k_copy16<<<dim3((960000+255)/256), dim3(256), 0, stream>>>(
            (ulong2*)xsnap, (const ulong2*)nodes, 960000);
        k_spmm_csr<<<dim3(60000/4), dim3(256), 0, stream>>>(nodes, acc, Gptr, Gcv, xsnap, 60000);
    }
    // local = acc/3
    k_scale<<<dim3((NND+255)/256), dim3(256), 0, stream>>>(acc, NND);

    // global hypergraph branch
    k_initg<<<dim3((PD+255)/256), dim3(256), 0, stream>>>(xg, accg, nodes_emb, PD);
    k_zero<<<dim3((12500+255)/256), dim3(256), 0, stream>>>((float*)cntH, 12500); // 50000 ints
    k_hist<<<dim3(NNZH/256), dim3(256), 0, stream>>>(cntH, HG_rows, NNZH);
    k_scan<<<dim3(1), dim3(1024), 0, stream>>>(cntH, Hptr, 50000);
    k_initcurB<<<dim3(13), dim3(256), 0, stream>>>(curBH, Hptr, 3125);
    k_append<<<dim3(NNZH/256), dim3(256), 0, stream>>>(stageH, curBH, HG_rows, HG_cols, HG_vals, NNZH);
    k_place<<<dim3(3125), dim3(256), 0, stream>>>(Hcv, Hptr, stageH, 50000);
    for (int it = 0; it < 2; it++){
        k_copy16<<<dim3((800000+255)/256), dim3(256), 0, stream>>>(
            (ulong2*)xsnapg, (const ulong2*)xg, 800000);
        k_spmm_csr<<<dim3(50000/4), dim3(256), 0, stream>>>(xg, accg, Hptr, Hcv, xsnapg, 50000);
    }
    // fusion: pois rows of acc += accg/3, emit pois output (overwrites dead scratch in out)
    k_fusion<<<dim3((PD+255)/256), dim3(256), 0, stream>>>(acc + (size_t)NUSERS*128, accg, out + BATCH*128, PD);

    // ===== head (f32 path) =====
    k_gather_f<<<dim3((BL*128+255)/256), dim3(256), 0, stream>>>(H1f, acc, rev_seqs, BL);
    k_hs<<<dim3(BATCH), dim3(128), 0, stream>>>(hs, H1f, lens);
    k_mgemm<float,float><<<dim3(BATCH/128), dim3(256), 0, stream>>>(
        hs, glu2_w, 128, 0, nullptr, 0, hproj, 0, nullptr, 0, nullptr, nullptr);
    k_posw<<<dim3(SEQL+1), dim3(128), 0, stream>>>(posW, pos_emb_glob, w1_w);
    // nh1 = tanh(H1f @ w1_w[:,128:]^T + posW[pidx] + w1_b)
    k_mgemm<float,bf16><<<dim3(BL/128), dim3(256), 0, stream>>>(
        H1f, w1_w, 256, 128, w1_b, 0, nh, 2, posW, 1, masks, nullptr);
    // beta = sum_c sigmoid(nh@glu1_w^T + glu1_b + hproj)·w2  (nh2 never stored)
    k_nh2beta<<<dim3(BL/128), dim3(256), 0, stream>>>(nh, glu1_w, glu1_b, hproj, w_2, betaB);
    k_final<<<dim3(BATCH), dim3(128), 0, stream>>>(out, betaB, H1f, acc, uidx);
}